// Round 1
// 85.645 us; speedup vs baseline: 1.0001x; 1.0001x over previous
//
#include <hip/hip_runtime.h>
#include <math.h>

#define BB 8
#define HH 256
#define WW 256
#define T  2     // rows per fused block (must divide 64)
#define NW 4     // 256 rows / 64 bits
#define PAD 96   // envelope window padding; R>PAD handled by exact fallback
#define LDSW (WW + 2 * PAD)

typedef unsigned long long u64;

// ---------------------------------------------------------------------------
// K0: per-column class presence bitmasks + zero the output accumulator.
// NEW layout (k innermost, vector-friendly):
//   masks[((b*NW + w)*WW + x)*4 + k] bit ly  <=>  tgt[b][w*64+ly][x] == k
// Each thread stores 32 contiguous bytes -> 2x global_store_dwordx4.
// ---------------------------------------------------------------------------
__global__ __launch_bounds__(256) void build_masks(const int* __restrict__ tgt,
                                                   u64* __restrict__ masks,
                                                   float* __restrict__ out) {
  const int x = threadIdx.x;
  const int b = blockIdx.x;
  const int w = blockIdx.y;
  if (b == 0 && w == 0 && x == 0) out[0] = 0.0f;  // ordered before fused's atomics
  u64 m0 = 0, m1 = 0, m2 = 0, m3 = 0, bit = 1ull;
  const int* p = tgt + ((size_t)b * HH + w * 64) * WW + x;
  for (int ly = 0; ly < 64; ++ly, bit += bit) {
    int e = p[ly * WW];                 // coalesced across x, L2-resident
    m0 |= (e == 0) ? bit : 0ull;
    m1 |= (e == 1) ? bit : 0ull;
    m2 |= (e == 2) ? bit : 0ull;
    m3 |= (e == 3) ? bit : 0ull;
  }
  u64* mp = masks + ((size_t)(b * NW + w) * WW + x) * 4;
  ulonglong2 lo, hi;
  lo.x = m0; lo.y = m1;
  hi.x = m2; hi.y = m3;
  *(ulonglong2*)(mp + 0) = lo;
  *(ulonglong2*)(mp + 2) = hi;
}

// ---------------------------------------------------------------------------
// K1 fused: bitmask column-EDT -> padded LDS -> exact +/- paired envelope
// (per-wave radius) -> softmax epilogue -> block reduce -> one atomicAdd.
// dist-to-neg(c) == min_{j != c} dist-to-class(j): only 4 maps needed.
// Changes vs R0: k-contiguous mask loads (8x dwordx4), register-carried
// envelope seeds (no LDS re-read), epilogue operands prefetched before the
// envelope loop so their memory latency hides under envelope compute.
// ---------------------------------------------------------------------------
__global__ __launch_bounds__(256, 4) void fused(const u64* __restrict__ masks,
                                                const int* __restrict__ tgt,
                                                const float* __restrict__ preds,
                                                float* __restrict__ out) {
  __shared__ float g[T][LDSW][4];   // squared 1-D column distances, padded rows
  __shared__ float fred[4];
  const int x  = threadIdx.x;
  const int b  = blockIdx.x;
  const int y0 = blockIdx.y * T;
  const int wy = y0 >> 6;           // T divides 64 -> same word for all tile rows

  // init padding to +INF (disjoint from the g[.][x+PAD] slots written below)
  for (int i = x; i < T * 2 * PAD; i += 256) {
    int j = i / (2 * PAD);
    int q = i - j * (2 * PAD);
    int idx = (q < PAD) ? q : (q + WW);
    *(float4*)&g[j][idx][0] = make_float4(1e30f, 1e30f, 1e30f, 1e30f);
  }

  // column masks for this x: 4 words x 4 classes, 32 B contiguous per thread
  u64 m[NW][4];
  {
    const u64* mb = masks + ((size_t)b * NW * WW + x) * 4;
#pragma unroll
    for (int w = 0; w < NW; ++w) {
      ulonglong2 lo = *(const ulonglong2*)(mb + (size_t)w * WW * 4 + 0);
      ulonglong2 hi = *(const ulonglong2*)(mb + (size_t)w * WW * 4 + 2);
      m[w][0] = lo.x; m[w][1] = lo.y; m[w][2] = hi.x; m[w][3] = hi.y;
    }
  }

  // phase A: exact 1-D distance along the column via nearest-set-bit
  // (identical math to R2 of the previous session, verified absmax 0.0)
  float d[T][4];                    // envelope seeds carried in registers
  int lmax = 0;
#pragma unroll
  for (int j = 0; j < T; ++j) {
    const int y  = y0 + j;
    const int ly = y & 63;
    const int ini = min(513 + y, 768 - y);   // reference INF-scan value
    float4 gv;
    float* gp = (float*)&gv;
#pragma unroll
    for (int k = 0; k < 4; ++k) {
      int best = ini;
#pragma unroll
      for (int w = 0; w < NW; ++w) {
        u64 bits = m[w][k];
        if (w < wy) {              // wave-uniform branch (wy is scalar)
          int dd = y - (w * 64 + 63 - __clzll((long long)bits));
          best = min(best, bits ? dd : 1024);
        } else if (w > wy) {
          int dd = w * 64 + (__ffsll((long long)bits) - 1) - y;
          best = min(best, bits ? dd : 1024);
        } else {
          u64 lo = bits & ((2ull << ly) - 1ull);  // bits 0..ly (ly=63 -> ~0)
          u64 hi = bits >> ly;                    // bit0 == bit ly
          int dl = ly - 63 + __clzll((long long)lo);
          int dh = __ffsll((long long)hi) - 1;
          best = min(best, lo ? dl : 1024);
          best = min(best, hi ? dh : 1024);
        }
      }
      lmax = max(lmax, best);
      gp[k] = (float)(best * best);
      d[j][k] = gp[k];             // kk = 0 seed, no LDS round-trip
    }
    *(float4*)&g[j][x + PAD][0] = gv;
  }

  // per-wave radius: for pixel x, candidate |kk| >= dist(x) can't beat the
  // kk=0 seed (kk^2 >= g[x]); dist(x) <= wave-max over own lanes. Exact.
#pragma unroll
  for (int off = 32; off; off >>= 1) lmax = max(lmax, __shfl_xor(lmax, off, 64));
  const int R  = __builtin_amdgcn_readfirstlane(lmax);
  const int Rw = min(R, PAD);
  __syncthreads();

  // prefetch epilogue operands now; latency hides under the envelope loop
  float pr[T][4];
  int   tt[T];
#pragma unroll
  for (int j = 0; j < T; ++j) {
    const int y = y0 + j;
    tt[j] = tgt[((size_t)b * HH + y) * WW + x];
    const float* pb = preds + ((size_t)b * 4 * HH + y) * WW + x;
    pr[j][0] = pb[0 * HH * WW];
    pr[j][1] = pb[1 * HH * WW];
    pr[j][2] = pb[2 * HH * WW];
    pr[j][3] = pb[3 * HH * WW];
  }

  // exact lower envelope, +/- paired, wave-uniform dx^2
  for (int kk = 1; kk <= Rw; ++kk) {
    float fkk = (float)kk;
    float fk2 = fkk * fkk;
#pragma unroll
    for (int j = 0; j < T; ++j) {
      float4 gm = *(const float4*)&g[j][x + PAD - kk][0];
      float4 gp = *(const float4*)&g[j][x + PAD + kk][0];
      d[j][0] = fminf(d[j][0], fminf(gm.x, gp.x) + fk2);
      d[j][1] = fminf(d[j][1], fminf(gm.y, gp.y) + fk2);
      d[j][2] = fminf(d[j][2], fminf(gm.z, gp.z) + fk2);
      d[j][3] = fminf(d[j][3], fminf(gm.w, gp.w) + fk2);
    }
  }
  if (R > PAD) {                       // exactness fallback; never hot
#pragma unroll 1
    for (int kk = PAD + 1; kk <= R; ++kk) {
      int xm = max(x - kk, 0), xp = min(x + kk, WW - 1);
      float dm = (float)(x - xm), dpq = (float)(xp - x);
      float dm2 = dm * dm, dp2 = dpq * dpq;
#pragma unroll
      for (int j = 0; j < T; ++j) {
        float4 gm = *(const float4*)&g[j][xm + PAD][0];
        float4 gp = *(const float4*)&g[j][xp + PAD][0];
        d[j][0] = fminf(d[j][0], fminf(gm.x + dm2, gp.x + dp2));
        d[j][1] = fminf(d[j][1], fminf(gm.y + dm2, gp.y + dp2));
        d[j][2] = fminf(d[j][2], fminf(gm.z + dm2, gp.z + dp2));
        d[j][3] = fminf(d[j][3], fminf(gm.w + dm2, gp.w + dp2));
      }
    }
  }

  // epilogue: softmax + boundary map (same math as the verified kernel)
  float acc = 0.0f;
#pragma unroll
  for (int j = 0; j < T; ++j) {
    const int t = tt[j];
    float p0 = pr[j][0], p1 = pr[j][1], p2 = pr[j][2], p3 = pr[j][3];
    float pm = fmaxf(fmaxf(p0, p1), fmaxf(p2, p3));
    float e0 = expf(p0 - pm), e1 = expf(p1 - pm);
    float e2 = expf(p2 - pm), e3 = expf(p3 - pm);
    float inv = 1.0f / (e0 + e1 + e2 + e3);

    float dn1 = fminf(d[j][0], fminf(d[j][2], d[j][3]));
    float dn2 = fminf(d[j][0], fminf(d[j][1], d[j][3]));
    float dn3 = fminf(d[j][0], fminf(d[j][1], d[j][2]));
    float c1 = (t == 1) ? (1.0f - sqrtf(dn1)) : sqrtf(d[j][1]);
    float c2 = (t == 2) ? (1.0f - sqrtf(dn2)) : sqrtf(d[j][2]);
    float c3 = (t == 3) ? (1.0f - sqrtf(dn3)) : sqrtf(d[j][3]);
    acc += (c1 * e1 + c2 * e2 + c3 * e3) * inv;
  }

  // block reduction -> single atomic
#pragma unroll
  for (int off = 32; off; off >>= 1) acc += __shfl_down(acc, off, 64);
  if ((x & 63) == 0) fred[x >> 6] = acc;
  __syncthreads();
  if (x == 0)
    atomicAdd(out, (fred[0] + fred[1] + fred[2] + fred[3]) *
                       (1.0f / (3.0f * BB * HH * WW)));
}

extern "C" void kernel_launch(void* const* d_in, const int* in_sizes, int n_in,
                              void* d_out, int out_size, void* d_ws, size_t ws_size,
                              hipStream_t stream) {
  const float* preds = (const float*)d_in[0];
  const int*   tgt   = (const int*)d_in[1];
  float* out   = (float*)d_out;
  u64*   masks = (u64*)d_ws;   // 8*4*256*4*8B = 256 KB

  build_masks<<<dim3(BB, NW), 256, 0, stream>>>(tgt, masks, out);
  fused<<<dim3(BB, HH / T), 256, 0, stream>>>(masks, tgt, preds, out);
}

// Round 2
// 80.592 us; speedup vs baseline: 1.0628x; 1.0627x over previous
//
#include <hip/hip_runtime.h>
#include <math.h>

#define BB 8
#define HH 256
#define WW 256
#define T  2     // rows per fused block (must divide 64)
#define NW 4     // 256 rows / 64 bits
#define PAD 96   // envelope window padding; R>PAD handled by exact fallback
#define LDSW (WW + 2 * PAD)

typedef unsigned long long u64;

// ---------------------------------------------------------------------------
// K0: per-column class presence bitmasks + zero the output accumulator.
// Layout (k innermost): masks[((b*NW + w)*WW + x)*4 + k] bit ly  <=>
//   tgt[b][w*64+ly][x] == k.
// R2 change: 2x parallelism. Each block builds a 32-row u32 HALF-WORD
// (z = 0 -> bits 0..31, z = 1 -> bits 32..63). The two halves of a u64 are
// disjoint 4-byte stores, so no merge is needed. 64 blocks instead of 32.
// ---------------------------------------------------------------------------
__global__ __launch_bounds__(256) void build_masks(const int* __restrict__ tgt,
                                                   unsigned* __restrict__ masks32,
                                                   float* __restrict__ out) {
  const int x = threadIdx.x;
  const int b = blockIdx.x;
  const int w = blockIdx.y;
  const int h = blockIdx.z;                     // row half within the word
  if (b == 0 && w == 0 && h == 0 && x == 0) out[0] = 0.0f;
  unsigned m0 = 0, m1 = 0, m2 = 0, m3 = 0, bit = 1u;
  const int* p = tgt + ((size_t)b * HH + w * 64 + h * 32) * WW + x;
  for (int r = 0; r < 32; ++r, bit += bit) {
    int e = p[r * WW];                          // coalesced across x
    m0 |= (e == 0) ? bit : 0u;
    m1 |= (e == 1) ? bit : 0u;
    m2 |= (e == 2) ? bit : 0u;
    m3 |= (e == 3) ? bit : 0u;
  }
  unsigned* mp = masks32 + (((size_t)(b * NW + w) * WW + x) * 4) * 2 + h;
  mp[0] = m0;   // class 0, this half (little-endian u64: half 0 = bits 0..31)
  mp[2] = m1;
  mp[4] = m2;
  mp[6] = m3;
}

// ---------------------------------------------------------------------------
// K1 fused: bitmask column-EDT -> padded LDS -> exact +/- paired envelope
// -> softmax epilogue -> block reduce -> one atomicAdd.
// R2 changes: (1) dynamic wave-wide early exit in the envelope — break when
// kk^2 >= max over all lanes/rows/classes of current d (exact: every
// remaining candidate adds >= (kk+1)^2 >= current d); (2) epilogue target
// class derived from the resident mask word (removes the tgt global read).
// ---------------------------------------------------------------------------
__global__ __launch_bounds__(256, 4) void fused(const u64* __restrict__ masks,
                                                const float* __restrict__ preds,
                                                float* __restrict__ out) {
  __shared__ float g[T][LDSW][4];   // squared 1-D column distances, padded rows
  __shared__ float fred[4];
  const int x  = threadIdx.x;
  const int b  = blockIdx.x;
  const int y0 = blockIdx.y * T;
  const int wy = y0 >> 6;           // T divides 64 -> same word for all tile rows

  // column masks for this x: 4 words x 4 classes, 32 B contiguous per thread
  u64 m[NW][4];
  {
    const u64* mb = masks + ((size_t)b * NW * WW + x) * 4;
#pragma unroll
    for (int w = 0; w < NW; ++w) {
      ulonglong2 lo = *(const ulonglong2*)(mb + (size_t)w * WW * 4 + 0);
      ulonglong2 hi = *(const ulonglong2*)(mb + (size_t)w * WW * 4 + 2);
      m[w][0] = lo.x; m[w][1] = lo.y; m[w][2] = hi.x; m[w][3] = hi.y;
    }
  }

  // prefetch epilogue preds now; latency hides under phase A + envelope
  float pr[T][4];
#pragma unroll
  for (int j = 0; j < T; ++j) {
    const float* pb = preds + ((size_t)b * 4 * HH + (y0 + j)) * WW + x;
    pr[j][0] = pb[0 * HH * WW];
    pr[j][1] = pb[1 * HH * WW];
    pr[j][2] = pb[2 * HH * WW];
    pr[j][3] = pb[3 * HH * WW];
  }

  // init padding to +INF (disjoint from the g[.][x+PAD] slots written below)
  for (int i = x; i < T * 2 * PAD; i += 256) {
    int j = i / (2 * PAD);
    int q = i - j * (2 * PAD);
    int idx = (q < PAD) ? q : (q + WW);
    *(float4*)&g[j][idx][0] = make_float4(1e30f, 1e30f, 1e30f, 1e30f);
  }

  // phase A: exact 1-D distance along the column via nearest-set-bit
  float d[T][4];                    // envelope seeds carried in registers
  int lmax = 0;
#pragma unroll
  for (int j = 0; j < T; ++j) {
    const int y  = y0 + j;
    const int ly = y & 63;
    const int ini = min(513 + y, 768 - y);   // reference INF-scan value
    float4 gv;
    float* gp = (float*)&gv;
#pragma unroll
    for (int k = 0; k < 4; ++k) {
      int best = ini;
#pragma unroll
      for (int w = 0; w < NW; ++w) {
        u64 bits = m[w][k];
        if (w < wy) {              // wave-uniform branch (wy is scalar)
          int dd = y - (w * 64 + 63 - __clzll((long long)bits));
          best = min(best, bits ? dd : 1024);
        } else if (w > wy) {
          int dd = w * 64 + (__ffsll((long long)bits) - 1) - y;
          best = min(best, bits ? dd : 1024);
        } else {
          u64 lo = bits & ((2ull << ly) - 1ull);  // bits 0..ly (ly=63 -> ~0)
          u64 hi = bits >> ly;                    // bit0 == bit ly
          int dl = ly - 63 + __clzll((long long)lo);
          int dh = __ffsll((long long)hi) - 1;
          best = min(best, lo ? dl : 1024);
          best = min(best, hi ? dh : 1024);
        }
      }
      lmax = max(lmax, best);
      gp[k] = (float)(best * best);
      d[j][k] = gp[k];             // kk = 0 seed, no LDS round-trip
    }
    *(float4*)&g[j][x + PAD][0] = gv;
  }

  // per-wave static radius bound (upper bound; dynamic break usually earlier)
#pragma unroll
  for (int off = 32; off; off >>= 1) lmax = max(lmax, __shfl_xor(lmax, off, 64));
  const int R  = __builtin_amdgcn_readfirstlane(lmax);
  const int Rw = min(R, PAD);
  __syncthreads();

  // exact lower envelope, +/- paired, wave-uniform dx^2, dynamic early exit:
  // once kk^2 >= d for every lane/row/class, all remaining candidates
  // (g >= 0, offset >= (kk+1)^2) are dominated -> break is exact.
  bool alldone = false;
  for (int kk = 1; kk <= Rw; ++kk) {
    float fkk = (float)kk;
    float fk2 = fkk * fkk;
    float dmax = 0.0f;
#pragma unroll
    for (int j = 0; j < T; ++j) {
      float4 gm = *(const float4*)&g[j][x + PAD - kk][0];
      float4 gp = *(const float4*)&g[j][x + PAD + kk][0];
      d[j][0] = fminf(d[j][0], fminf(gm.x, gp.x) + fk2);
      d[j][1] = fminf(d[j][1], fminf(gm.y, gp.y) + fk2);
      d[j][2] = fminf(d[j][2], fminf(gm.z, gp.z) + fk2);
      d[j][3] = fminf(d[j][3], fminf(gm.w, gp.w) + fk2);
      dmax = fmaxf(dmax, fmaxf(fmaxf(d[j][0], d[j][1]), fmaxf(d[j][2], d[j][3])));
    }
    if (__all(dmax <= fk2)) { alldone = true; break; }
  }
  if (!alldone && R > PAD) {           // exactness fallback; never hot
#pragma unroll 1
    for (int kk = PAD + 1; kk <= R; ++kk) {
      int xm = max(x - kk, 0), xp = min(x + kk, WW - 1);
      float dm = (float)(x - xm), dpq = (float)(xp - x);
      float dm2 = dm * dm, dp2 = dpq * dpq;
      float dmax = 0.0f;
#pragma unroll
      for (int j = 0; j < T; ++j) {
        float4 gm = *(const float4*)&g[j][xm + PAD][0];
        float4 gp = *(const float4*)&g[j][xp + PAD][0];
        d[j][0] = fminf(d[j][0], fminf(gm.x + dm2, gp.x + dp2));
        d[j][1] = fminf(d[j][1], fminf(gm.y + dm2, gp.y + dp2));
        d[j][2] = fminf(d[j][2], fminf(gm.z + dm2, gp.z + dp2));
        d[j][3] = fminf(d[j][3], fminf(gm.w + dm2, gp.w + dp2));
        dmax = fmaxf(dmax, fmaxf(fmaxf(d[j][0], d[j][1]), fmaxf(d[j][2], d[j][3])));
      }
      float fkk = (float)kk;
      if (__all(dmax <= fkk * fkk)) break;
    }
  }

  // epilogue: softmax + boundary map; target class from the resident mask word
  float acc = 0.0f;
#pragma unroll
  for (int j = 0; j < T; ++j) {
    const int ly = (y0 + j) & 63;
    const int t = (int)((m[wy][1] >> ly) & 1ull) * 1 +
                  (int)((m[wy][2] >> ly) & 1ull) * 2 +
                  (int)((m[wy][3] >> ly) & 1ull) * 3;
    float p0 = pr[j][0], p1 = pr[j][1], p2 = pr[j][2], p3 = pr[j][3];
    float pm = fmaxf(fmaxf(p0, p1), fmaxf(p2, p3));
    float e0 = expf(p0 - pm), e1 = expf(p1 - pm);
    float e2 = expf(p2 - pm), e3 = expf(p3 - pm);
    float inv = 1.0f / (e0 + e1 + e2 + e3);

    float dn1 = fminf(d[j][0], fminf(d[j][2], d[j][3]));
    float dn2 = fminf(d[j][0], fminf(d[j][1], d[j][3]));
    float dn3 = fminf(d[j][0], fminf(d[j][1], d[j][2]));
    float c1 = (t == 1) ? (1.0f - sqrtf(dn1)) : sqrtf(d[j][1]);
    float c2 = (t == 2) ? (1.0f - sqrtf(dn2)) : sqrtf(d[j][2]);
    float c3 = (t == 3) ? (1.0f - sqrtf(dn3)) : sqrtf(d[j][3]);
    acc += (c1 * e1 + c2 * e2 + c3 * e3) * inv;
  }

  // block reduction -> single atomic
#pragma unroll
  for (int off = 32; off; off >>= 1) acc += __shfl_down(acc, off, 64);
  if ((x & 63) == 0) fred[x >> 6] = acc;
  __syncthreads();
  if (x == 0)
    atomicAdd(out, (fred[0] + fred[1] + fred[2] + fred[3]) *
                       (1.0f / (3.0f * BB * HH * WW)));
}

extern "C" void kernel_launch(void* const* d_in, const int* in_sizes, int n_in,
                              void* d_out, int out_size, void* d_ws, size_t ws_size,
                              hipStream_t stream) {
  const float* preds = (const float*)d_in[0];
  const int*   tgt   = (const int*)d_in[1];
  float* out   = (float*)d_out;
  u64*   masks = (u64*)d_ws;   // 8*4*256*4*8B = 256 KB

  build_masks<<<dim3(BB, NW, 2), 256, 0, stream>>>(tgt, (unsigned*)masks, out);
  fused<<<dim3(BB, HH / T), 256, 0, stream>>>(masks, preds, out);
}

// Round 3
// 79.760 us; speedup vs baseline: 1.0739x; 1.0104x over previous
//
#include <hip/hip_runtime.h>
#include <math.h>

#define BB 8
#define HH 256
#define WW 256
#define T  2     // rows per fused block (must divide 64)
#define NW 4     // 256 rows / 64 bits
#define PAD 96   // envelope window padding; R>PAD handled by exact fallback
#define LDSW (WW + 2 * PAD)

typedef unsigned long long u64;

// ---------------------------------------------------------------------------
// K0: per-column class presence bitmasks + zero the output accumulator.
// u64 layout (k innermost, unchanged): masks[((b*NW + w)*WW + x)*4 + k]
//   bit ly <=> tgt[b][w*64+ly][x] == k.
// R3 change: 4x more parallelism again. 256 blocks x 128 threads; each
// thread builds a 16-row u16 QUARTER-word (q = bits q*16..q*16+15 of the
// little-endian u64). Quarters are disjoint 2-byte stores, so no merge.
// CU coverage 100% (was 25%); 16 loads/thread (was 32).
// ---------------------------------------------------------------------------
__global__ __launch_bounds__(128) void build_masks(const int* __restrict__ tgt,
                                                   unsigned short* __restrict__ masks16,
                                                   float* __restrict__ out) {
  const int tx = threadIdx.x;           // 0..127
  const int xh = blockIdx.x & 1;        // x half
  const int b  = blockIdx.x >> 1;
  const int w  = blockIdx.y;            // u64 word = 64 rows
  const int q  = blockIdx.z;            // quarter: rows w*64+q*16 .. +15
  const int x  = xh * 128 + tx;
  if (b == 0 && w == 0 && q == 0 && x == 0) out[0] = 0.0f;
  unsigned m0 = 0, m1 = 0, m2 = 0, m3 = 0, bit = 1u;
  const int* p = tgt + ((size_t)b * HH + w * 64 + q * 16) * WW + x;
  for (int r = 0; r < 16; ++r, bit += bit) {
    int e = p[r * WW];                  // coalesced across x
    m0 |= (e == 0) ? bit : 0u;
    m1 |= (e == 1) ? bit : 0u;
    m2 |= (e == 2) ? bit : 0u;
    m3 |= (e == 3) ? bit : 0u;
  }
  // u16 index = u64_index*4 + q ; u64_index = ((b*NW+w)*WW+x)*4 + k
  unsigned short* mp = masks16 + (((size_t)(b * NW + w) * WW + x) * 4) * 4 + q;
  mp[0]  = (unsigned short)m0;          // k = 0
  mp[4]  = (unsigned short)m1;          // k = 1
  mp[8]  = (unsigned short)m2;          // k = 2
  mp[12] = (unsigned short)m3;          // k = 3
}

// ---------------------------------------------------------------------------
// K1 fused (unchanged from R2, verified absmax 0.0): bitmask column-EDT ->
// padded LDS -> exact +/- paired envelope with dynamic wave-wide early exit
// -> softmax epilogue (target class from resident mask word) -> block reduce
// -> one atomicAdd.
// ---------------------------------------------------------------------------
__global__ __launch_bounds__(256, 4) void fused(const u64* __restrict__ masks,
                                                const float* __restrict__ preds,
                                                float* __restrict__ out) {
  __shared__ float g[T][LDSW][4];   // squared 1-D column distances, padded rows
  __shared__ float fred[4];
  const int x  = threadIdx.x;
  const int b  = blockIdx.x;
  const int y0 = blockIdx.y * T;
  const int wy = y0 >> 6;           // T divides 64 -> same word for all tile rows

  // column masks for this x: 4 words x 4 classes, 32 B contiguous per thread
  u64 m[NW][4];
  {
    const u64* mb = masks + ((size_t)b * NW * WW + x) * 4;
#pragma unroll
    for (int w = 0; w < NW; ++w) {
      ulonglong2 lo = *(const ulonglong2*)(mb + (size_t)w * WW * 4 + 0);
      ulonglong2 hi = *(const ulonglong2*)(mb + (size_t)w * WW * 4 + 2);
      m[w][0] = lo.x; m[w][1] = lo.y; m[w][2] = hi.x; m[w][3] = hi.y;
    }
  }

  // prefetch epilogue preds now; latency hides under phase A + envelope
  float pr[T][4];
#pragma unroll
  for (int j = 0; j < T; ++j) {
    const float* pb = preds + ((size_t)b * 4 * HH + (y0 + j)) * WW + x;
    pr[j][0] = pb[0 * HH * WW];
    pr[j][1] = pb[1 * HH * WW];
    pr[j][2] = pb[2 * HH * WW];
    pr[j][3] = pb[3 * HH * WW];
  }

  // init padding to +INF (disjoint from the g[.][x+PAD] slots written below)
  for (int i = x; i < T * 2 * PAD; i += 256) {
    int j = i / (2 * PAD);
    int q = i - j * (2 * PAD);
    int idx = (q < PAD) ? q : (q + WW);
    *(float4*)&g[j][idx][0] = make_float4(1e30f, 1e30f, 1e30f, 1e30f);
  }

  // phase A: exact 1-D distance along the column via nearest-set-bit
  float d[T][4];                    // envelope seeds carried in registers
  int lmax = 0;
#pragma unroll
  for (int j = 0; j < T; ++j) {
    const int y  = y0 + j;
    const int ly = y & 63;
    const int ini = min(513 + y, 768 - y);   // reference INF-scan value
    float4 gv;
    float* gp = (float*)&gv;
#pragma unroll
    for (int k = 0; k < 4; ++k) {
      int best = ini;
#pragma unroll
      for (int w = 0; w < NW; ++w) {
        u64 bits = m[w][k];
        if (w < wy) {              // wave-uniform branch (wy is scalar)
          int dd = y - (w * 64 + 63 - __clzll((long long)bits));
          best = min(best, bits ? dd : 1024);
        } else if (w > wy) {
          int dd = w * 64 + (__ffsll((long long)bits) - 1) - y;
          best = min(best, bits ? dd : 1024);
        } else {
          u64 lo = bits & ((2ull << ly) - 1ull);  // bits 0..ly (ly=63 -> ~0)
          u64 hi = bits >> ly;                    // bit0 == bit ly
          int dl = ly - 63 + __clzll((long long)lo);
          int dh = __ffsll((long long)hi) - 1;
          best = min(best, lo ? dl : 1024);
          best = min(best, hi ? dh : 1024);
        }
      }
      lmax = max(lmax, best);
      gp[k] = (float)(best * best);
      d[j][k] = gp[k];             // kk = 0 seed, no LDS round-trip
    }
    *(float4*)&g[j][x + PAD][0] = gv;
  }

  // per-wave static radius bound (upper bound; dynamic break usually earlier)
#pragma unroll
  for (int off = 32; off; off >>= 1) lmax = max(lmax, __shfl_xor(lmax, off, 64));
  const int R  = __builtin_amdgcn_readfirstlane(lmax);
  const int Rw = min(R, PAD);
  __syncthreads();

  // exact lower envelope, +/- paired, wave-uniform dx^2, dynamic early exit:
  // once kk^2 >= d for every lane/row/class, all remaining candidates
  // (g >= 0, offset >= (kk+1)^2) are dominated -> break is exact.
  bool alldone = false;
  for (int kk = 1; kk <= Rw; ++kk) {
    float fkk = (float)kk;
    float fk2 = fkk * fkk;
    float dmax = 0.0f;
#pragma unroll
    for (int j = 0; j < T; ++j) {
      float4 gm = *(const float4*)&g[j][x + PAD - kk][0];
      float4 gp = *(const float4*)&g[j][x + PAD + kk][0];
      d[j][0] = fminf(d[j][0], fminf(gm.x, gp.x) + fk2);
      d[j][1] = fminf(d[j][1], fminf(gm.y, gp.y) + fk2);
      d[j][2] = fminf(d[j][2], fminf(gm.z, gp.z) + fk2);
      d[j][3] = fminf(d[j][3], fminf(gm.w, gp.w) + fk2);
      dmax = fmaxf(dmax, fmaxf(fmaxf(d[j][0], d[j][1]), fmaxf(d[j][2], d[j][3])));
    }
    if (__all(dmax <= fk2)) { alldone = true; break; }
  }
  if (!alldone && R > PAD) {           // exactness fallback; never hot
#pragma unroll 1
    for (int kk = PAD + 1; kk <= R; ++kk) {
      int xm = max(x - kk, 0), xp = min(x + kk, WW - 1);
      float dm = (float)(x - xm), dpq = (float)(xp - x);
      float dm2 = dm * dm, dp2 = dpq * dpq;
      float dmax = 0.0f;
#pragma unroll
      for (int j = 0; j < T; ++j) {
        float4 gm = *(const float4*)&g[j][xm + PAD][0];
        float4 gp = *(const float4*)&g[j][xp + PAD][0];
        d[j][0] = fminf(d[j][0], fminf(gm.x + dm2, gp.x + dp2));
        d[j][1] = fminf(d[j][1], fminf(gm.y + dm2, gp.y + dp2));
        d[j][2] = fminf(d[j][2], fminf(gm.z + dm2, gp.z + dp2));
        d[j][3] = fminf(d[j][3], fminf(gm.w + dm2, gp.w + dp2));
        dmax = fmaxf(dmax, fmaxf(fmaxf(d[j][0], d[j][1]), fmaxf(d[j][2], d[j][3])));
      }
      float fkk = (float)kk;
      if (__all(dmax <= fkk * fkk)) break;
    }
  }

  // epilogue: softmax + boundary map; target class from the resident mask word
  float acc = 0.0f;
#pragma unroll
  for (int j = 0; j < T; ++j) {
    const int ly = (y0 + j) & 63;
    const int t = (int)((m[wy][1] >> ly) & 1ull) * 1 +
                  (int)((m[wy][2] >> ly) & 1ull) * 2 +
                  (int)((m[wy][3] >> ly) & 1ull) * 3;
    float p0 = pr[j][0], p1 = pr[j][1], p2 = pr[j][2], p3 = pr[j][3];
    float pm = fmaxf(fmaxf(p0, p1), fmaxf(p2, p3));
    float e0 = expf(p0 - pm), e1 = expf(p1 - pm);
    float e2 = expf(p2 - pm), e3 = expf(p3 - pm);
    float inv = 1.0f / (e0 + e1 + e2 + e3);

    float dn1 = fminf(d[j][0], fminf(d[j][2], d[j][3]));
    float dn2 = fminf(d[j][0], fminf(d[j][1], d[j][3]));
    float dn3 = fminf(d[j][0], fminf(d[j][1], d[j][2]));
    float c1 = (t == 1) ? (1.0f - sqrtf(dn1)) : sqrtf(d[j][1]);
    float c2 = (t == 2) ? (1.0f - sqrtf(dn2)) : sqrtf(d[j][2]);
    float c3 = (t == 3) ? (1.0f - sqrtf(dn3)) : sqrtf(d[j][3]);
    acc += (c1 * e1 + c2 * e2 + c3 * e3) * inv;
  }

  // block reduction -> single atomic
#pragma unroll
  for (int off = 32; off; off >>= 1) acc += __shfl_down(acc, off, 64);
  if ((x & 63) == 0) fred[x >> 6] = acc;
  __syncthreads();
  if (x == 0)
    atomicAdd(out, (fred[0] + fred[1] + fred[2] + fred[3]) *
                       (1.0f / (3.0f * BB * HH * WW)));
}

extern "C" void kernel_launch(void* const* d_in, const int* in_sizes, int n_in,
                              void* d_out, int out_size, void* d_ws, size_t ws_size,
                              hipStream_t stream) {
  const float* preds = (const float*)d_in[0];
  const int*   tgt   = (const int*)d_in[1];
  float* out   = (float*)d_out;
  u64*   masks = (u64*)d_ws;   // 8*4*256*4*8B = 256 KB

  build_masks<<<dim3(BB * 2, NW, 4), 128, 0, stream>>>(tgt, (unsigned short*)masks, out);
  fused<<<dim3(BB, HH / T), 256, 0, stream>>>(masks, preds, out);
}

// Round 4
// 72.493 us; speedup vs baseline: 1.1816x; 1.1002x over previous
//
#include <hip/hip_runtime.h>
#include <math.h>

#define BB 8
#define HH 256
#define WW 256
#define T  4     // rows per fused block (must divide 64)
#define NW 4     // 256 rows / 64 bits
#define PAD 96   // envelope window padding; R>PAD handled by exact fallback
#define LDSW (WW + 2 * PAD)

typedef unsigned long long u64;

// ---------------------------------------------------------------------------
// K0 (unchanged from R3, verified): per-column class presence bitmasks +
// zero the output accumulator. u64 layout (k innermost):
//   masks[((b*NW + w)*WW + x)*4 + k] bit ly <=> tgt[b][w*64+ly][x] == k.
// 256 blocks x 128 threads; each thread builds a 16-row u16 quarter-word.
// ---------------------------------------------------------------------------
__global__ __launch_bounds__(128) void build_masks(const int* __restrict__ tgt,
                                                   unsigned short* __restrict__ masks16,
                                                   float* __restrict__ out) {
  const int tx = threadIdx.x;           // 0..127
  const int xh = blockIdx.x & 1;        // x half
  const int b  = blockIdx.x >> 1;
  const int w  = blockIdx.y;            // u64 word = 64 rows
  const int q  = blockIdx.z;            // quarter: rows w*64+q*16 .. +15
  const int x  = xh * 128 + tx;
  if (b == 0 && w == 0 && q == 0 && x == 0) out[0] = 0.0f;
  unsigned m0 = 0, m1 = 0, m2 = 0, m3 = 0, bit = 1u;
  const int* p = tgt + ((size_t)b * HH + w * 64 + q * 16) * WW + x;
  for (int r = 0; r < 16; ++r, bit += bit) {
    int e = p[r * WW];                  // coalesced across x
    m0 |= (e == 0) ? bit : 0u;
    m1 |= (e == 1) ? bit : 0u;
    m2 |= (e == 2) ? bit : 0u;
    m3 |= (e == 3) ? bit : 0u;
  }
  unsigned short* mp = masks16 + (((size_t)(b * NW + w) * WW + x) * 4) * 4 + q;
  mp[0]  = (unsigned short)m0;          // k = 0
  mp[4]  = (unsigned short)m1;          // k = 1
  mp[8]  = (unsigned short)m2;          // k = 2
  mp[12] = (unsigned short)m3;          // k = 3
}

// ---------------------------------------------------------------------------
// K1 fused. R4 changes: T=4 (halves block count, mask redundancy, atomics);
// phase A shares non-own-word nearest-bit positions across all 4 rows
// (posmax/posmin per class are row-independent); envelope uses PER-LANE
// deactivation (lane stops once kk^2 >= max of its d — same dominance
// argument as the wave-wide exit, so still exact).
// ---------------------------------------------------------------------------
__global__ __launch_bounds__(256, 2) void fused(const u64* __restrict__ masks,
                                                const float* __restrict__ preds,
                                                float* __restrict__ out) {
  __shared__ float g[T][LDSW][4];   // squared 1-D column distances, padded rows
  __shared__ float fred[4];
  const int x  = threadIdx.x;
  const int b  = blockIdx.x;
  const int y0 = blockIdx.y * T;
  const int wy = y0 >> 6;           // T divides 64 -> same word for all tile rows

  // column masks for this x: 4 words x 4 classes, 32 B contiguous per thread
  u64 m[NW][4];
  {
    const u64* mb = masks + ((size_t)b * NW * WW + x) * 4;
#pragma unroll
    for (int w = 0; w < NW; ++w) {
      ulonglong2 lo = *(const ulonglong2*)(mb + (size_t)w * WW * 4 + 0);
      ulonglong2 hi = *(const ulonglong2*)(mb + (size_t)w * WW * 4 + 2);
      m[w][0] = lo.x; m[w][1] = lo.y; m[w][2] = hi.x; m[w][3] = hi.y;
    }
  }

  // prefetch epilogue preds now; latency hides under phase A + envelope
  float pr[T][4];
#pragma unroll
  for (int j = 0; j < T; ++j) {
    const float* pb = preds + ((size_t)b * 4 * HH + (y0 + j)) * WW + x;
    pr[j][0] = pb[0 * HH * WW];
    pr[j][1] = pb[1 * HH * WW];
    pr[j][2] = pb[2 * HH * WW];
    pr[j][3] = pb[3 * HH * WW];
  }

  // init padding to +INF (disjoint from the g[.][x+PAD] slots written below)
  for (int i = x; i < T * 2 * PAD; i += 256) {
    int j = i / (2 * PAD);
    int q = i - j * (2 * PAD);
    int idx = (q < PAD) ? q : (q + WW);
    *(float4*)&g[j][idx][0] = make_float4(1e30f, 1e30f, 1e30f, 1e30f);
  }

  // phase A part 1: non-own words' nearest-bit positions, shared by all rows.
  // Sentinels (-4096 / 8192) always lose to the ini cap, like the old 1024.
  int posmax[4] = {-4096, -4096, -4096, -4096};
  int posmin[4] = { 8192,  8192,  8192,  8192};
#pragma unroll
  for (int w = 0; w < NW; ++w) {
    if (w < wy) {                    // wave-uniform branch (wy is scalar)
#pragma unroll
      for (int k = 0; k < 4; ++k) {
        u64 bits = m[w][k];
        int pos = w * 64 + 63 - __clzll((long long)bits);
        posmax[k] = max(posmax[k], bits ? pos : -4096);
      }
    } else if (w > wy) {
#pragma unroll
      for (int k = 0; k < 4; ++k) {
        u64 bits = m[w][k];
        int pos = w * 64 + (__ffsll((long long)bits) - 1);
        posmin[k] = min(posmin[k], bits ? pos : 8192);
      }
    }
  }

  // phase A part 2: per-row own-word eval + combine (exact, as verified)
  float d[T][4];                    // envelope seeds carried in registers
  int lmax = 0;
#pragma unroll
  for (int j = 0; j < T; ++j) {
    const int y  = y0 + j;
    const int ly = y & 63;
    const int ini = min(513 + y, 768 - y);   // reference INF-scan value
    float4 gv;
    float* gp_ = (float*)&gv;
#pragma unroll
    for (int k = 0; k < 4; ++k) {
      u64 bits = m[wy][k];
      u64 lo = bits & ((2ull << ly) - 1ull);  // bits 0..ly (ly=63 -> ~0)
      u64 hi = bits >> ly;                    // bit0 == bit ly
      int dl = ly - 63 + __clzll((long long)lo);
      int dh = __ffsll((long long)hi) - 1;
      int best = min(ini, y - posmax[k]);
      best = min(best, posmin[k] - y);
      best = min(best, lo ? dl : 1024);
      best = min(best, hi ? dh : 1024);
      lmax = max(lmax, best);
      float fb = (float)(best * best);
      gp_[k] = fb;
      d[j][k] = fb;                // kk = 0 seed, no LDS round-trip
    }
    *(float4*)&g[j][x + PAD][0] = gv;
  }

  // per-wave static radius bound (upper bound; per-lane exit usually earlier)
#pragma unroll
  for (int off = 32; off; off >>= 1) lmax = max(lmax, __shfl_xor(lmax, off, 64));
  const int R  = __builtin_amdgcn_readfirstlane(lmax);
  const int Rw = min(R, PAD);
  __syncthreads();

  // per-lane running bound: max over this lane's d (monotone decreasing)
  float mydone = 0.0f;
#pragma unroll
  for (int j = 0; j < T; ++j)
    mydone = fmaxf(mydone,
                   fmaxf(fmaxf(d[j][0], d[j][1]), fmaxf(d[j][2], d[j][3])));

  // exact lower envelope, +/- paired, wave-uniform dx^2.
  // Lane deactivates once kk^2 >= mydone (all its remaining candidates are
  // dominated: g >= 0 so candidate >= kk^2 >= current d). Wave breaks when
  // every lane is inactive. Inactive lanes issue no LDS fetches (exec mask).
  bool alldone = false;
  for (int kk = 1; kk <= Rw; ++kk) {
    float fkk = (float)kk;
    float fk2 = fkk * fkk;
    bool act = (mydone > fk2);
    if (__all(!act)) { alldone = true; break; }
    if (act) {
#pragma unroll
      for (int j = 0; j < T; ++j) {
        float4 gm = *(const float4*)&g[j][x + PAD - kk][0];
        float4 gq = *(const float4*)&g[j][x + PAD + kk][0];
        d[j][0] = fminf(d[j][0], fminf(gm.x, gq.x) + fk2);
        d[j][1] = fminf(d[j][1], fminf(gm.y, gq.y) + fk2);
        d[j][2] = fminf(d[j][2], fminf(gm.z, gq.z) + fk2);
        d[j][3] = fminf(d[j][3], fminf(gm.w, gq.w) + fk2);
      }
      float md = 0.0f;
#pragma unroll
      for (int j = 0; j < T; ++j)
        md = fmaxf(md, fmaxf(fmaxf(d[j][0], d[j][1]), fmaxf(d[j][2], d[j][3])));
      mydone = md;
    }
  }
  if (!alldone && R > PAD) {           // exactness fallback; never hot
#pragma unroll 1
    for (int kk = PAD + 1; kk <= R; ++kk) {
      float fkk = (float)kk;
      float fk2 = fkk * fkk;
      bool act = (mydone > fk2);
      if (__all(!act)) break;
      if (act) {
        int xm = max(x - kk, 0), xp = min(x + kk, WW - 1);
        float dm = (float)(x - xm), dpq = (float)(xp - x);
        float dm2 = dm * dm, dp2 = dpq * dpq;
#pragma unroll
        for (int j = 0; j < T; ++j) {
          float4 gm = *(const float4*)&g[j][xm + PAD][0];
          float4 gq = *(const float4*)&g[j][xp + PAD][0];
          d[j][0] = fminf(d[j][0], fminf(gm.x + dm2, gq.x + dp2));
          d[j][1] = fminf(d[j][1], fminf(gm.y + dm2, gq.y + dp2));
          d[j][2] = fminf(d[j][2], fminf(gm.z + dm2, gq.z + dp2));
          d[j][3] = fminf(d[j][3], fminf(gm.w + dm2, gq.w + dp2));
        }
        float md = 0.0f;
#pragma unroll
        for (int j = 0; j < T; ++j)
          md = fmaxf(md, fmaxf(fmaxf(d[j][0], d[j][1]), fmaxf(d[j][2], d[j][3])));
        mydone = md;
      }
    }
  }

  // epilogue: softmax + boundary map; target class from the resident mask word
  float acc = 0.0f;
#pragma unroll
  for (int j = 0; j < T; ++j) {
    const int ly = (y0 + j) & 63;
    const int t = (int)((m[wy][1] >> ly) & 1ull) * 1 +
                  (int)((m[wy][2] >> ly) & 1ull) * 2 +
                  (int)((m[wy][3] >> ly) & 1ull) * 3;
    float p0 = pr[j][0], p1 = pr[j][1], p2 = pr[j][2], p3 = pr[j][3];
    float pm = fmaxf(fmaxf(p0, p1), fmaxf(p2, p3));
    float e0 = expf(p0 - pm), e1 = expf(p1 - pm);
    float e2 = expf(p2 - pm), e3 = expf(p3 - pm);
    float inv = 1.0f / (e0 + e1 + e2 + e3);

    float dn1 = fminf(d[j][0], fminf(d[j][2], d[j][3]));
    float dn2 = fminf(d[j][0], fminf(d[j][1], d[j][3]));
    float dn3 = fminf(d[j][0], fminf(d[j][1], d[j][2]));
    float c1 = (t == 1) ? (1.0f - sqrtf(dn1)) : sqrtf(d[j][1]);
    float c2 = (t == 2) ? (1.0f - sqrtf(dn2)) : sqrtf(d[j][2]);
    float c3 = (t == 3) ? (1.0f - sqrtf(dn3)) : sqrtf(d[j][3]);
    acc += (c1 * e1 + c2 * e2 + c3 * e3) * inv;
  }

  // block reduction -> single atomic
#pragma unroll
  for (int off = 32; off; off >>= 1) acc += __shfl_down(acc, off, 64);
  if ((x & 63) == 0) fred[x >> 6] = acc;
  __syncthreads();
  if (x == 0)
    atomicAdd(out, (fred[0] + fred[1] + fred[2] + fred[3]) *
                       (1.0f / (3.0f * BB * HH * WW)));
}

extern "C" void kernel_launch(void* const* d_in, const int* in_sizes, int n_in,
                              void* d_out, int out_size, void* d_ws, size_t ws_size,
                              hipStream_t stream) {
  const float* preds = (const float*)d_in[0];
  const int*   tgt   = (const int*)d_in[1];
  float* out   = (float*)d_out;
  u64*   masks = (u64*)d_ws;   // 8*4*256*4*8B = 256 KB

  build_masks<<<dim3(BB * 2, NW, 4), 128, 0, stream>>>(tgt, (unsigned short*)masks, out);
  fused<<<dim3(BB, HH / T), 256, 0, stream>>>(masks, preds, out);
}